// Round 4
// baseline (177.746 us; speedup 1.0000x reference)
//
#include <hip/hip_runtime.h>
#include <hip/hip_cooperative_groups.h>

namespace cg = cooperative_groups;

// Problem constants (from reference setup_inputs)
#define E_TOT 1000000
#define D_DIM 128
#define C_CAP 262144
#define N_IDS 16384
#define NB 102            // buckets: [key<0], keys 0..99, [key>=100]; 255 = protected
#define NW 31250          // miss bit words: E/32
#define NBLK 256          // cooperative grid: 1 block per CU
#define NTHR 512          // 8 waves per block
#define SLOTS_PER_BLK 1024 // C / NBLK; 2 slots per thread
#define MWB 62            // miss-scan blocks: ceil(NW/NTHR)

static_assert(NBLK * SLOTS_PER_BLK == C_CAP, "geometry");
static_assert(MWB * NTHR >= NW, "geometry");
static_assert(NB + MWB <= NBLK, "geometry");

// EXACT count of bytes in w equal to the (replicated) pattern byte.
// Per byte b of x = w^pat: y = ((b&0x7F)+0x7F) | b | 0x7F has bit7 set iff
// b != 0; (b&0x7F)+0x7F <= 0xFE so no carry crosses byte lanes (the previous
// version used the borrow-prone (x-0x01010101)&~x trick — boolean-only!).
__device__ __forceinline__ int cnt_eq(unsigned int w, unsigned int pat) {
    unsigned int x = w ^ pat;
    unsigned int y = ((x & 0x7F7F7F7Fu) + 0x7F7F7F7Fu) | x | 0x7F7F7F7Fu;
    return __popc(~y & 0x80808080u);
}

// 512-thread exclusive block scan (wave shfl scan + LDS wave sums).
// Caller guarantees whole block enters (branch is block-uniform).
__device__ __forceinline__ int block_exscan(int v, int tid, int* lds8) {
    int lane = tid & 63, wv = tid >> 6;
    int incl = v;
#pragma unroll
    for (int o = 1; o < 64; o <<= 1) {
        int u = __shfl_up(incl, o, 64);
        if (lane >= o) incl += u;
    }
    if (lane == 63) lds8[wv] = incl;
    __syncthreads();
    int wsum = 0;
    for (int w2 = 0; w2 < wv; ++w2) wsum += lds8[w2];
    __syncthreads();
    return wsum + incl - v;
}

__global__ __launch_bounds__(NTHR, 2) void fused_kernel(
    const int* __restrict__ ids,
    const int* __restrict__ idx_map,
    const int* __restrict__ cidx,
    const int* __restrict__ inv,
    const int* __restrict__ freq,
    const float* __restrict__ weight,
    const float* __restrict__ cuda_weight,
    float* __restrict__ out,
    unsigned int* __restrict__ protBits,
    unsigned int* __restrict__ missBits,
    int* __restrict__ bucketTotal,
    int* __restrict__ blockHist,
    int* __restrict__ wordPrefix,
    int* __restrict__ blockSumMiss,
    int* __restrict__ order)
{
    cg::grid_group grid = cg::this_grid();
    const int tid = threadIdx.x;
    const int bid = blockIdx.x;
    const int gtid = bid * NTHR + tid;

    __shared__ unsigned char ldsB[SLOTS_PER_BLK]; // per-slot bucket bytes
    __shared__ int waveHist[8][NB];               // per-wave bucket histogram
    __shared__ int lds8[8];                       // wave sums for block scans

    // ---------------- Z: zero accumulation state -------------------------
    if (gtid < C_CAP / 32) protBits[gtid] = 0;
    else if (gtid < C_CAP / 32 + NW) missBits[gtid - C_CAP / 32] = 0;
    else if (gtid < C_CAP / 32 + NW + NB) bucketTotal[gtid - C_CAP / 32 - NW] = 0;
    grid.sync();

    // ---------------- S: scatter batch presence --------------------------
    if (gtid < N_IDS) {
        int id = ids[gtid];
        if (id >= 0 && id < E_TOT) {
            int row = idx_map[id];
            if (row >= 0 && row < E_TOT) {
                int s = inv[row];
                if (s >= 0) {
                    if (s < C_CAP) atomicOr(&protBits[s >> 5], 1u << (s & 31));
                } else {
                    atomicOr(&missBits[row >> 5], 1u << (row & 31));
                }
            }
        }
    }
    grid.sync();

    // ---------------- C: bucket + stable in-block rank --------------------
    int bA, bB;        // bucket of my two slots (255 = protected)
    int rA = 0, rB = 0; // stable rank within block
    {
        const int s0 = bid * SLOTS_PER_BLK + 2 * tid;
        {
            int b0, b1;
            if ((protBits[s0 >> 5] >> (s0 & 31)) & 1u) b0 = 255;
            else {
                int crow = cidx[s0];
                int key = (crow < 0) ? -1 : freq[crow < E_TOT ? crow : (E_TOT - 1)];
                b0 = (key < 0) ? 0 : (key >= 100 ? 101 : key + 1);
            }
            int s1 = s0 + 1;
            if ((protBits[s1 >> 5] >> (s1 & 31)) & 1u) b1 = 255;
            else {
                int crow = cidx[s1];
                int key = (crow < 0) ? -1 : freq[crow < E_TOT ? crow : (E_TOT - 1)];
                b1 = (key < 0) ? 0 : (key >= 100 ? 101 : key + 1);
            }
            bA = b0; bB = b1;
        }
        ldsB[2 * tid]     = (unsigned char)bA;
        ldsB[2 * tid + 1] = (unsigned char)bB;
        for (int k = tid; k < 8 * NB; k += NTHR) ((int*)waveHist)[k] = 0;
        __syncthreads();
        const int wv = tid >> 6, lane = tid & 63;
        if (bA != 255) atomicAdd(&waveHist[wv][bA], 1);
        if (bB != 255) atomicAdd(&waveHist[wv][bB], 1);
        __syncthreads();
        // in-wave rank: count equal bucket bytes before my slots in the
        // wave's 128-byte segment of ldsB
        const unsigned int* wp = (const unsigned int*)&ldsB[wv * 128];
        unsigned int patA = 0x01010101u * (unsigned)bA;
        unsigned int patB = 0x01010101u * (unsigned)bB;
        int full = lane >> 1; // (2*lane)/4 full words
        int cA = 0, cB = 0;
        for (int w = 0; w < full; ++w) {
            unsigned int x = wp[w];
            cA += cnt_eq(x, patA);
            cB += cnt_eq(x, patB);
        }
        if (lane & 1) { // 2 leftover bytes; upper bytes -> 0xFF (never match b<255)
            unsigned int x = wp[full] | 0xFFFF0000u;
            cA += cnt_eq(x, patA);
            cB += cnt_eq(x, patB);
        }
        int pA = 0, pB = 0;
        for (int w2 = 0; w2 < wv; ++w2) {
            pA += (bA != 255) ? waveHist[w2][bA] : 0;
            pB += (bB != 255) ? waveHist[w2][bB] : 0;
        }
        rA = pA + cA;
        rB = pB + cB + ((bA == bB) ? 1 : 0);
        // per-block histogram -> global; bucket totals via deterministic sums
        if (tid < NB) {
            int s = 0;
#pragma unroll
            for (int w2 = 0; w2 < 8; ++w2) s += waveHist[w2][tid];
            blockHist[bid * NB + tid] = s;
            atomicAdd(&bucketTotal[tid], s);
        }
    }
    grid.sync();

    // ---------------- X: cross-block scans (parallel over blocks) ---------
    if (bid < NB) {
        // exclusive scan over NBLK blocks of blockHist[:, bid]
        int v = (tid < NBLK) ? blockHist[tid * NB + bid] : 0;
        int excl = block_exscan(v, tid, lds8);
        if (tid < NBLK) blockHist[tid * NB + bid] = excl;
    } else if (bid < NB + MWB) {
        int j = bid - NB;
        int w = j * NTHR + tid;
        int v = (w < NW) ? __popc(missBits[w]) : 0;
        int excl = block_exscan(v, tid, lds8);
        if (w < NW) wordPrefix[w] = excl;
        if (tid == NTHR - 1) blockSumMiss[j] = excl + v;
    }
    grid.sync();

    // ---------------- P: place + wordPrefix fixup -------------------------
    {
        // cross-block miss prefix fixup
        if (gtid < NW) {
            int j = gtid >> 9; // / NTHR
            int add = 0;
            for (int k = 0; k < j; ++k) add += blockSumMiss[k];
            wordPrefix[gtid] += add;
        }
        if (bA != 255 || bB != 255) {
            int m = 0;
            for (int k = 0; k < MWB; ++k) m += blockSumMiss[k];
            // bucket starts (exclusive prefix of bucketTotal) for bA, bB
            int tA = (bA == 255) ? -1 : bA;
            int tB = (bB == 255) ? -1 : bB;
            int bmax = tA > tB ? tA : tB;
            int bsA = 0, bsB = 0, run = 0;
            for (int b = 0; b <= bmax; ++b) {
                if (b == tA) bsA = run;
                if (b == tB) bsB = run;
                run += bucketTotal[b];
            }
            const int s0 = bid * SLOTS_PER_BLK + 2 * tid;
            if (bA != 255) {
                int pos = bsA + blockHist[bid * NB + bA] + rA;
                if (pos < m) order[pos] = s0;
            }
            if (bB != 255) {
                int pos = bsB + blockHist[bid * NB + bB] + rB;
                if (pos < m) order[pos] = s0 + 1;
            }
        }
    }
    grid.sync();

    // ---------------- F: translation + row gather -------------------------
    {
        const int wv = gtid >> 6;   // 0..2047
        const int lane = gtid & 63;
        for (int i = wv; i < N_IDS; i += (NBLK * NTHR) / 64) {
            int id = ids[i];
            int row = (id >= 0 && id < E_TOT) ? idx_map[id] : 0;
            row = row < 0 ? 0 : (row >= E_TOT ? E_TOT - 1 : row);
            int s0 = inv[row];
            int slot;
            const float* src;
            if (s0 >= 0) {
                slot = s0;
                src = cuda_weight + (size_t)slot * D_DIM;
            } else {
                int w = row >> 5;
                unsigned int mask = (1u << (row & 31)) - 1u;
                int rank = wordPrefix[w] + __popc(missBits[w] & mask);
                rank = rank < 0 ? 0 : (rank >= N_IDS ? N_IDS - 1 : rank);
                slot = order[rank];
                src = weight + (size_t)row * D_DIM;
            }
            if (lane == 0) out[i] = (float)slot;
            const float2* s2 = (const float2*)src;
            float2* d2 = (float2*)(out + N_IDS + (size_t)i * D_DIM);
            d2[lane] = s2[lane];
        }
    }
}

// ---------------------------------------------------------------------------
extern "C" void kernel_launch(void* const* d_in, const int* in_sizes, int n_in,
                              void* d_out, int out_size, void* d_ws, size_t ws_size,
                              hipStream_t stream) {
    const int* ids     = (const int*)d_in[0];
    const int* idx_map = (const int*)d_in[1];
    const int* cidx    = (const int*)d_in[2]; // cached_idx_map
    const int* inv     = (const int*)d_in[3]; // inverted_cached_idx
    const int* freq    = (const int*)d_in[4]; // freq_cnter
    const float* weight      = (const float*)d_in[5];
    const float* cuda_weight = (const float*)d_in[6];
    float* out = (float*)d_out;

    unsigned char* ws = (unsigned char*)d_ws;
    size_t o = 0;
    auto take = [&](size_t bytes) {
        size_t r = o;
        o += (bytes + 255) & ~(size_t)255;
        return r;
    };
    unsigned int* protBits = (unsigned int*)(ws + take(C_CAP / 8));      // 32 KB
    unsigned int* missBits = (unsigned int*)(ws + take((size_t)NW * 4)); // 125 KB
    int* bucketTotal  = (int*)(ws + take(NB * 4));
    int* blockHist    = (int*)(ws + take((size_t)NBLK * NB * 4));        // 104 KB
    int* wordPrefix   = (int*)(ws + take((size_t)NW * 4));               // 125 KB
    int* blockSumMiss = (int*)(ws + take(MWB * 4));
    int* order        = (int*)(ws + take((size_t)N_IDS * 4));            // 64 KB
    (void)ws_size; (void)in_sizes; (void)n_in; (void)out_size;

    void* args[] = {
        (void*)&ids, (void*)&idx_map, (void*)&cidx, (void*)&inv, (void*)&freq,
        (void*)&weight, (void*)&cuda_weight, (void*)&out,
        (void*)&protBits, (void*)&missBits, (void*)&bucketTotal,
        (void*)&blockHist, (void*)&wordPrefix, (void*)&blockSumMiss,
        (void*)&order
    };
    hipLaunchCooperativeKernel((void*)fused_kernel, dim3(NBLK), dim3(NTHR),
                               args, 0, stream);
}

// Round 5
// 35.214 us; speedup vs baseline: 5.0476x; 5.0476x over previous
//
#include <hip/hip_runtime.h>

// Problem constants (from reference setup_inputs)
#define E_TOT 1000000
#define D_DIM 128
#define C_CAP 262144
#define N_IDS 16384
#define NB 102        // buckets: [key<0], keys 0..99, [key>=100]; 255 = protected
#define NW 31250      // miss bit words: E/32
#define SB 256        // slot blocks (C / SPB)
#define NTHR 512
#define SPB 1024      // slots per slot-block (2 per thread)
#define MWB 62        // miss-scan blocks: 62*512 >= NW
#define CHK 52        // blockHist chunk: 5 chunks cover 256 blocks

static_assert(SB * SPB == C_CAP, "geometry");
static_assert(MWB * NTHR >= NW, "geometry");
static_assert(5 * CHK >= SB, "geometry");
static_assert(5 * NB <= NTHR, "geometry");

// EXACT per-byte equality count (carry-free SWAR; validated R4)
__device__ __forceinline__ int cnt_eq(unsigned w, unsigned pat) {
    unsigned x = w ^ pat;
    unsigned y = ((x & 0x7F7F7F7Fu) + 0x7F7F7F7Fu) | x | 0x7F7F7F7Fu;
    return __popc(~y & 0x80808080u);
}

__device__ __forceinline__ int bucket_of(int crow, const int* __restrict__ freq) {
    int key = (crow < 0) ? -1 : freq[crow < E_TOT ? crow : (E_TOT - 1)];
    return (key < 0) ? 0 : (key >= 100 ? 101 : key + 1);
}

// 512-thread exclusive block scan (wave shfl scan + LDS wave sums);
// block-uniform entry only.
__device__ __forceinline__ int block_exscan(int v, int tid, int* lds8) {
    int lane = tid & 63, wv = tid >> 6;
    int incl = v;
#pragma unroll
    for (int o = 1; o < 64; o <<= 1) {
        int u = __shfl_up(incl, o, 64);
        if (lane >= o) incl += u;
    }
    if (lane == 63) lds8[wv] = incl;
    __syncthreads();
    int wsum = 0;
    for (int w = 0; w < wv; ++w) wsum += lds8[w];
    __syncthreads();
    return wsum + incl - v;
}

// ---------------------------------------------------------------------------
// D2: scatter batch presence into bitmasks (atomicOr = idempotent)
__global__ __launch_bounds__(256) void scatter_k(
    const int* __restrict__ ids, const int* __restrict__ idx_map,
    const int* __restrict__ inv, unsigned* __restrict__ protBits,
    unsigned* __restrict__ missBits) {
    int i = blockIdx.x * 256 + threadIdx.x; // grid exactly N_IDS threads
    int id = ids[i];
    if (id < 0 || id >= E_TOT) return;
    int row = idx_map[id];
    if (row < 0 || row >= E_TOT) return;
    int s = inv[row];
    if (s >= 0) {
        if (s < C_CAP) atomicOr(&protBits[s >> 5], 1u << (s & 31));
    } else {
        atomicOr(&missBits[row >> 5], 1u << (row & 31));
    }
}

// ---------------------------------------------------------------------------
// D3: blocks [0,SB): per-slot bucket byte + per-block bucket histogram
//     blocks [SB,SB+MWB): per-chunk miss popcount exclusive scans
__global__ __launch_bounds__(NTHR) void count_k(
    const unsigned* __restrict__ protBits, const int* __restrict__ cidx,
    const int* __restrict__ freq, const unsigned* __restrict__ missBits,
    unsigned short* __restrict__ bucketArr2, int* __restrict__ blockHist,
    int* __restrict__ wordPrefix, int* __restrict__ blockSumMiss) {
    __shared__ int waveHist[8][NB];
    __shared__ int lds8[8];
    const int tid = threadIdx.x, bid = blockIdx.x;
    if (bid < SB) {
        for (int k = tid; k < 8 * NB; k += NTHR) ((int*)waveHist)[k] = 0;
        __syncthreads();
        const int s0 = bid * SPB + 2 * tid;          // even
        const int2 cr = *(const int2*)(cidx + s0);
        const unsigned pw = protBits[s0 >> 5];       // s0, s0+1 share word
        int b0 = ((pw >> (s0 & 31)) & 1u) ? 255 : bucket_of(cr.x, freq);
        int b1 = ((pw >> ((s0 & 31) + 1)) & 1u) ? 255 : bucket_of(cr.y, freq);
        const int wv = tid >> 6;
        if (b0 != 255) atomicAdd(&waveHist[wv][b0], 1);
        if (b1 != 255) atomicAdd(&waveHist[wv][b1], 1);
        bucketArr2[bid * (SPB / 2) + tid] = (unsigned short)(b0 | (b1 << 8));
        __syncthreads();
        if (tid < NB) {
            int s = 0;
#pragma unroll
            for (int w = 0; w < 8; ++w) s += waveHist[w][tid];
            blockHist[bid * NB + tid] = s;
        }
    } else {
        const int j = bid - SB;
        const int w = j * NTHR + tid;
        int v = (w < NW) ? __popc(missBits[w]) : 0;
        int excl = block_exscan(v, tid, lds8);
        if (w < NW) wordPrefix[w] = excl;
        if (tid == NTHR - 1) blockSumMiss[j] = excl + v;
    }
}

// ---------------------------------------------------------------------------
// D4: blocks [0,SB): stable in-block rank + cross-block offsets -> order[]
//     blocks [SB,SB+MWB): wordPrefix cross-chunk fixup
__global__ __launch_bounds__(NTHR) void place_k(
    const unsigned short* __restrict__ bucketArr2,
    const int* __restrict__ blockHist, const int* __restrict__ blockSumMiss,
    int* __restrict__ wordPrefix, int* __restrict__ order) {
    const int tid = threadIdx.x, bid = blockIdx.x;
    if (bid < SB) {
        __shared__ unsigned char ldsB[SPB];
        __shared__ int waveHist[8][NB];
        __shared__ int partBefore[5][NB];
        __shared__ int partTotal[5][NB];
        __shared__ int bstart[NB];
        __shared__ int before[NB];
        __shared__ int mTot;
        ((unsigned short*)ldsB)[tid] = bucketArr2[bid * (SPB / 2) + tid];
        for (int k = tid; k < 8 * NB; k += NTHR) ((int*)waveHist)[k] = 0;
        __syncthreads();
        const int b0 = ldsB[2 * tid], b1 = ldsB[2 * tid + 1];
        const int wv = tid >> 6, lane = tid & 63;
        if (b0 != 255) atomicAdd(&waveHist[wv][b0], 1);
        if (b1 != 255) atomicAdd(&waveHist[wv][b1], 1);
        // stream blockHist: per-bucket totals + prefix over blocks < bid
        if (tid < 5 * NB) {
            const int c = tid / NB, b = tid % NB; // coalesced in b
            int lo = c * CHK, hi = lo + CHK;
            if (hi > SB) hi = SB;
            int tot = 0, bef = 0;
            for (int blk = lo; blk < hi; ++blk) {
                int v = blockHist[blk * NB + b];
                tot += v;
                if (blk < bid) bef += v;
            }
            partTotal[c][b] = tot;
            partBefore[c][b] = bef;
        }
        __syncthreads();
        if (tid < NB) {
            int t = 0, bf = 0;
#pragma unroll
            for (int c = 0; c < 5; ++c) {
                t += partTotal[c][tid];
                bf += partBefore[c][tid];
            }
            bstart[tid] = t; // temp: per-bucket grand total
            before[tid] = bf;
        }
        __syncthreads();
        if (tid == 0) { // exclusive scan of totals -> bucket starts
            int run = 0;
            for (int b = 0; b < NB; ++b) {
                int t = bstart[b];
                bstart[b] = run;
                run += t;
            }
        } else if (tid == 64) {
            int m = 0;
            for (int k = 0; k < MWB; ++k) m += blockSumMiss[k];
            mTot = m;
        }
        __syncthreads();
        const int m = mTot;
        // in-wave stable ranks over the wave's 128-byte ldsB segment
        const unsigned* wp = (const unsigned*)&ldsB[wv * 128];
        unsigned patA = 0x01010101u * (unsigned)b0;
        unsigned patB = 0x01010101u * (unsigned)b1;
        int full = lane >> 1;
        int cA = 0, cB = 0;
        for (int w = 0; w < full; ++w) {
            unsigned x = wp[w];
            cA += cnt_eq(x, patA);
            cB += cnt_eq(x, patB);
        }
        if (lane & 1) { // 2 leftover bytes; upper -> 0xFF (never match b<255)
            unsigned x = wp[full] | 0xFFFF0000u;
            cA += cnt_eq(x, patA);
            cB += cnt_eq(x, patB);
        }
        int pA = 0, pB = 0;
        for (int w = 0; w < wv; ++w) {
            pA += (b0 != 255) ? waveHist[w][b0] : 0;
            pB += (b1 != 255) ? waveHist[w][b1] : 0;
        }
        const int s0 = bid * SPB + 2 * tid;
        if (b0 != 255) {
            int pos = bstart[b0] + before[b0] + pA + cA;
            if (pos < m) order[pos] = s0;
        }
        if (b1 != 255) {
            int pos = bstart[b1] + before[b1] + pB + cB + ((b0 == b1) ? 1 : 0);
            if (pos < m) order[pos] = s0 + 1;
        }
    } else {
        const int j = bid - SB;
        int add = 0;
        for (int k = 0; k < j; ++k) add += blockSumMiss[k];
        const int w = j * NTHR + tid;
        if (w < NW) wordPrefix[w] += add;
    }
}

// ---------------------------------------------------------------------------
// D5: translation + row gather; one wave per row.
// d_out[0:N) = (float)gpu_row_idxs ; d_out[N:] = gathered f32 rows
__global__ __launch_bounds__(NTHR) void final_k(
    const int* __restrict__ ids, const int* __restrict__ idx_map,
    const int* __restrict__ inv, const unsigned* __restrict__ missBits,
    const int* __restrict__ wordPrefix, const int* __restrict__ order,
    const float* __restrict__ weight, const float* __restrict__ cuda_weight,
    float* __restrict__ out) {
    const int i = blockIdx.x * 8 + (threadIdx.x >> 6); // wave index = row
    const int lane = threadIdx.x & 63;
    int id = ids[i];
    int row = (id >= 0 && id < E_TOT) ? idx_map[id] : 0;
    row = row < 0 ? 0 : (row >= E_TOT ? E_TOT - 1 : row);
    int s0 = inv[row];
    int slot;
    const float* src;
    if (s0 >= 0) {
        slot = s0;
        src = cuda_weight + (size_t)slot * D_DIM;
    } else {
        int w = row >> 5;
        unsigned mask = (1u << (row & 31)) - 1u;
        int rank = wordPrefix[w] + __popc(missBits[w] & mask);
        rank = rank < 0 ? 0 : (rank >= N_IDS ? N_IDS - 1 : rank);
        slot = order[rank];
        src = weight + (size_t)row * D_DIM;
    }
    if (lane == 0) out[i] = (float)slot;
    const float2* s2 = (const float2*)src;
    float2* d2 = (float2*)(out + N_IDS + (size_t)i * D_DIM);
    d2[lane] = s2[lane]; // 64 lanes x float2 = 128 floats
}

// ---------------------------------------------------------------------------
extern "C" void kernel_launch(void* const* d_in, const int* in_sizes, int n_in,
                              void* d_out, int out_size, void* d_ws, size_t ws_size,
                              hipStream_t stream) {
    const int* ids     = (const int*)d_in[0];
    const int* idx_map = (const int*)d_in[1];
    const int* cidx    = (const int*)d_in[2]; // cached_idx_map
    const int* inv     = (const int*)d_in[3]; // inverted_cached_idx
    const int* freq    = (const int*)d_in[4]; // freq_cnter
    const float* weight      = (const float*)d_in[5];
    const float* cuda_weight = (const float*)d_in[6];
    float* out = (float*)d_out;

    unsigned char* ws = (unsigned char*)d_ws;
    size_t o = 0;
    auto take = [&](size_t bytes) {
        size_t r = o;
        o += (bytes + 255) & ~(size_t)255;
        return r;
    };
    // zero region first (one small contiguous memset)
    unsigned* protBits = (unsigned*)(ws + take(C_CAP / 8));        // 32 KB
    unsigned* missBits = (unsigned*)(ws + take((size_t)NW * 4));   // 125 KB
    size_t zbytes = o;
    unsigned short* bucketArr2 = (unsigned short*)(ws + take(C_CAP)); // 256 KB
    int* blockHist    = (int*)(ws + take((size_t)SB * NB * 4));    // 104 KB
    int* wordPrefix   = (int*)(ws + take((size_t)NW * 4));         // 125 KB
    int* blockSumMiss = (int*)(ws + take(MWB * 4));
    int* order        = (int*)(ws + take((size_t)N_IDS * 4));      // 64 KB
    (void)ws_size; (void)in_sizes; (void)n_in; (void)out_size;

    // D1: zero bitmasks
    hipMemsetAsync(ws, 0, zbytes, stream);

    // D2: presence scatter (exactly N_IDS threads)
    scatter_k<<<N_IDS / 256, 256, 0, stream>>>(ids, idx_map, inv, protBits,
                                               missBits);

    // D3: bucket bytes + per-block histograms | miss chunk scans
    count_k<<<SB + MWB, NTHR, 0, stream>>>(protBits, cidx, freq, missBits,
                                           bucketArr2, blockHist, wordPrefix,
                                           blockSumMiss);

    // D4: stable placement into order[0..m) | wordPrefix fixup
    place_k<<<SB + MWB, NTHR, 0, stream>>>(bucketArr2, blockHist, blockSumMiss,
                                           wordPrefix, order);

    // D5: translation + gather (one wave per row)
    final_k<<<N_IDS / 8, NTHR, 0, stream>>>(ids, idx_map, inv, missBits,
                                            wordPrefix, order, weight,
                                            cuda_weight, out);
}